// Round 13
// baseline (233.763 us; speedup 1.0000x reference)
//
#include <hip/hip_runtime.h>

#define DDIM 128
#define MSUB 8
#define KCODE 256
#define DSUB 16
#define NLIST 1024
#define NPROBE 32
#define TOPK 100
#define HBINS 4096
#define COLL_CAP 2048

// XLA/LLVM vectorized reduce, n=128, VF=16, IC=4:
// acc_l_j = p_{16l+j} + p_{64+16l+j}; combine (a0+a1)+(a2+a3); halving hsum 16->1.
__device__ __forceinline__ float xla_sumsq128(const float* x) {
  float s[16];
  #pragma unroll
  for (int j = 0; j < 16; ++j) {
    float p0 = __fmul_rn(x[j],       x[j]);
    float p1 = __fmul_rn(x[j + 16],  x[j + 16]);
    float p2 = __fmul_rn(x[j + 32],  x[j + 32]);
    float p3 = __fmul_rn(x[j + 48],  x[j + 48]);
    float p4 = __fmul_rn(x[j + 64],  x[j + 64]);
    float p5 = __fmul_rn(x[j + 80],  x[j + 80]);
    float p6 = __fmul_rn(x[j + 96],  x[j + 96]);
    float p7 = __fmul_rn(x[j + 112], x[j + 112]);
    float r0 = __fadd_rn(p0, p4);
    float r1 = __fadd_rn(p1, p5);
    float r2 = __fadd_rn(p2, p6);
    float r3 = __fadd_rn(p3, p7);
    s[j] = __fadd_rn(__fadd_rn(r0, r1), __fadd_rn(r2, r3));
  }
  float a[8], b[4], c[2];
  #pragma unroll
  for (int j = 0; j < 8; ++j) a[j] = __fadd_rn(s[j], s[j + 8]);
  #pragma unroll
  for (int j = 0; j < 4; ++j) b[j] = __fadd_rn(a[j], a[j + 4]);
  #pragma unroll
  for (int j = 0; j < 2; ++j) c[j] = __fadd_rn(b[j], b[j + 2]);
  return __fadd_rn(c[0], c[1]);
}

// XLA fused mul+reduce, n=16, VF=16: 16 rounded products, pure halving shuffle tree.
__device__ __forceinline__ float xla_sumsq16(const float* x) {
  float p[16];
  #pragma unroll
  for (int j = 0; j < 16; ++j) p[j] = __fmul_rn(x[j], x[j]);
  float s8[8], s4[4], s2[2];
  #pragma unroll
  for (int j = 0; j < 8; ++j) s8[j] = __fadd_rn(p[j], p[j + 8]);
  #pragma unroll
  for (int j = 0; j < 4; ++j) s4[j] = __fadd_rn(s8[j], s8[j + 4]);
  #pragma unroll
  for (int j = 0; j < 2; ++j) s2[j] = __fadd_rn(s4[j], s4[j + 2]);
  return __fadd_rn(s2[0], s2[1]);
}

// Eigen/BLAS GEMM dot: single FMA chain, k ascending
__device__ __forceinline__ float chain_dot16(const float* a, const float* b) {
  float dot = 0.f;
  #pragma unroll
  for (int d = 0; d < DSUB; ++d) dot = __fmaf_rn(a[d], b[d], dot);
  return dot;
}

// fp32 sequential adds m=0..7 (ref: l0 + l1 + ... each step rounded)
__device__ __forceinline__ float adc_dist(const float* lut, unsigned long long code) {
  float d = lut[(unsigned)(code & 255ULL)];
  d = __fadd_rn(d, lut[256  + (unsigned)((code >> 8)  & 255ULL)]);
  d = __fadd_rn(d, lut[512  + (unsigned)((code >> 16) & 255ULL)]);
  d = __fadd_rn(d, lut[768  + (unsigned)((code >> 24) & 255ULL)]);
  d = __fadd_rn(d, lut[1024 + (unsigned)((code >> 32) & 255ULL)]);
  d = __fadd_rn(d, lut[1280 + (unsigned)((code >> 40) & 255ULL)]);
  d = __fadd_rn(d, lut[1536 + (unsigned)((code >> 48) & 255ULL)]);
  d = __fadd_rn(d, lut[1792 + (unsigned)((code >> 56) & 255ULL)]);
  return d;
}

// ---------------- coarse: XLA reduce norms + GEMM chain dot ----------------
__global__ __launch_bounds__(256) void k_coarse(const float* __restrict__ queries,
                                                const float* __restrict__ centroids,
                                                int* __restrict__ probed) {
  const int qi = blockIdx.x;
  const int t = threadIdx.x;
  __shared__ float qs[DDIM];
  __shared__ unsigned long long keys[NLIST];
  __shared__ unsigned long long wred[4];
  if (t < DDIM) qs[t] = queries[qi * DDIM + t];
  __syncthreads();
  const float qq = xla_sumsq128(qs);

  for (int c = t; c < NLIST; c += 256) {
    const float* cr = centroids + (size_t)c * DDIM;
    float cbuf[DDIM];
    #pragma unroll
    for (int d = 0; d < DDIM; d += 4) {
      float4 cv = *(const float4*)(cr + d);
      cbuf[d] = cv.x; cbuf[d + 1] = cv.y; cbuf[d + 2] = cv.z; cbuf[d + 3] = cv.w;
    }
    const float cc = xla_sumsq128(cbuf);
    float dot = 0.f;
    #pragma unroll
    for (int d = 0; d < DDIM; ++d) dot = __fmaf_rn(qs[d], cbuf[d], dot);
    float dist = __fsub_rn(__fadd_rn(qq, cc), __fmul_rn(2.0f, dot));
    keys[c] = ((unsigned long long)__float_as_uint(dist) << 32) | (unsigned)c;
  }
  __syncthreads();
  for (int r = 0; r < NPROBE; ++r) {
    unsigned long long m = ~0ULL;
    for (int c = t; c < NLIST; c += 256) {
      unsigned long long k = keys[c];
      m = k < m ? k : m;
    }
    for (int off = 32; off > 0; off >>= 1) {
      unsigned lo = __shfl_down((unsigned)m, off, 64);
      unsigned hi = __shfl_down((unsigned)(m >> 32), off, 64);
      unsigned long long o = ((unsigned long long)hi << 32) | lo;
      m = o < m ? o : m;
    }
    if ((t & 63) == 0) wred[t >> 6] = m;
    __syncthreads();
    if (t == 0) {
      for (int w = 1; w < 4; ++w) m = wred[w] < m ? wred[w] : m;
      unsigned c = (unsigned)(m & 0xffffffffULL);
      probed[qi * NPROBE + r] = (int)c;
      keys[c] = ~0ULL;
    }
    __syncthreads();
  }
}

// ---------------- LUT: XLA halving16 norms + Eigen chain-FMA dot ----------------
__global__ __launch_bounds__(256) void k_lut(const float* __restrict__ queries,
                                             const float* __restrict__ codebooks,
                                             float* __restrict__ lut_g) {
  const int qi = blockIdx.x;
  const int t = threadIdx.x;
  __shared__ float qs[DDIM];
  if (t < DDIM) qs[t] = queries[qi * DDIM + t];
  __syncthreads();
  for (int j = 0; j < MSUB; ++j) {
    int idx = j * KCODE + t; // m=j, k=t
    const float* cb = codebooks + (size_t)idx * DSUB;
    const float* qsub = qs + j * DSUB;
    float cbv[DSUB], qv[DSUB];
    #pragma unroll
    for (int d = 0; d < DSUB; ++d) { cbv[d] = cb[d]; qv[d] = qsub[d]; }
    const float qq = xla_sumsq16(qv);
    const float cc = xla_sumsq16(cbv);
    const float dot = chain_dot16(qv, cbv);
    lut_g[(size_t)qi * (MSUB * KCODE) + idx] =
        __fsub_rn(__fadd_rn(qq, cc), __fmul_rn(2.0f, dot));
  }
}

// ---------------- counting sort of db by list id ----------------
__global__ __launch_bounds__(256) void k_hist(const int* __restrict__ db_list, int N,
                                              unsigned* __restrict__ counts) {
  __shared__ unsigned h[NLIST];
  const int t = threadIdx.x;
  for (int i = t; i < NLIST; i += 256) h[i] = 0;
  __syncthreads();
  for (int n = blockIdx.x * 256 + t; n < N; n += gridDim.x * 256)
    atomicAdd(&h[db_list[n]], 1u);
  __syncthreads();
  for (int i = t; i < NLIST; i += 256)
    if (h[i]) atomicAdd(&counts[i], h[i]);
}

__global__ __launch_bounds__(1024) void k_scan(const unsigned* __restrict__ counts,
                                               unsigned* __restrict__ bstart) {
  __shared__ unsigned s[NLIST];
  const int t = threadIdx.x;
  unsigned mine = counts[t];
  s[t] = mine;
  __syncthreads();
  for (int off = 1; off < NLIST; off <<= 1) {
    unsigned v = (t >= off) ? s[t - off] : 0u;
    __syncthreads();
    s[t] += v;
    __syncthreads();
  }
  bstart[t + 1] = s[t];
  if (t == 0) bstart[0] = 0;
}

__global__ __launch_bounds__(256) void k_scatter(const int* __restrict__ db_list,
                                                 const int* __restrict__ db_codes, int N,
                                                 const unsigned* __restrict__ bstart,
                                                 unsigned* __restrict__ cursor,
                                                 int* __restrict__ sorted_n,
                                                 unsigned long long* __restrict__ sorted_code) {
  for (int n = blockIdx.x * 256 + threadIdx.x; n < N; n += gridDim.x * 256) {
    int l = db_list[n];
    unsigned pos = bstart[l] + atomicAdd(&cursor[l], 1u);
    const int* c = db_codes + (size_t)n * MSUB;
    unsigned long long code = 0;
    for (int m = 0; m < MSUB; ++m)
      code |= ((unsigned long long)(unsigned)(c[m] & 255)) << (8 * m);
    sorted_n[pos] = n;
    sorted_code[pos] = code;
  }
}

// ---------------- main: one block per query ----------------
__global__ __launch_bounds__(256) void k_search(const float* __restrict__ lut_g,
                                                const int* __restrict__ probed,
                                                const unsigned* __restrict__ bstart,
                                                const int* __restrict__ sorted_n,
                                                const unsigned long long* __restrict__ sorted_code,
                                                int* __restrict__ out) {
  const int qi = blockIdx.x;
  const int t = threadIdx.x;
  __shared__ float lut_s[MSUB * KCODE];            // 8 KB
  __shared__ unsigned hist[HBINS];                 // 16 KB
  __shared__ unsigned long long coll[COLL_CAP];    // 16 KB: (fp32 bits << 32) | db_index
  __shared__ unsigned pstart[NPROBE], pcount[NPROBE];
  __shared__ unsigned part[256];
  __shared__ unsigned scnt;
  __shared__ int sT, sCb, sT2;

  for (int i = t; i < MSUB * KCODE; i += 256) lut_s[i] = lut_g[(size_t)qi * (MSUB * KCODE) + i];
  if (t < NPROBE) {
    int l = probed[qi * NPROBE + t];
    unsigned s0 = bstart[l];
    pstart[t] = s0;
    pcount[t] = bstart[l + 1] - s0;
  }
  for (int i = t; i < HBINS; i += 256) hist[i] = 0;
  if (t == 0) { scnt = 0; sT = HBINS - 1; sCb = 0; sT2 = HBINS - 1; }
  __syncthreads();

  // pass 1: histogram of fp32 bits[30:19]
  for (int j = 0; j < NPROBE; ++j) {
    unsigned s0 = pstart[j], cnt = pcount[j];
    for (unsigned i = t; i < cnt; i += 256) {
      float f = adc_dist(lut_s, sorted_code[s0 + i]);
      atomicAdd(&hist[__float_as_uint(f) >> 19], 1u);
    }
  }
  __syncthreads();

  // threshold bin T (rank TOPK) + count strictly below
  {
    unsigned mysum = 0;
    for (int i = 0; i < 16; ++i) mysum += hist[t * 16 + i];
    part[t] = mysum;
    __syncthreads();
    for (int off = 1; off < 256; off <<= 1) {
      unsigned v = (t >= off) ? part[t - off] : 0u;
      __syncthreads();
      part[t] += v;
      __syncthreads();
    }
    unsigned incl = part[t], excl = incl - mysum;
    if (excl < TOPK && TOPK <= incl) {
      unsigned c = excl;
      for (int i = 0; i < 16; ++i) {
        unsigned h = hist[t * 16 + i];
        if (c + h >= TOPK) { sT = t * 16 + i; sCb = (int)c; break; }
        c += h;
      }
    }
  }
  __syncthreads();
  const int T = sT;
  const unsigned cbelow = (unsigned)sCb;

  // refine within bin T on bits[18:7]
  for (int i = t; i < HBINS; i += 256) hist[i] = 0;
  __syncthreads();
  for (int j = 0; j < NPROBE; ++j) {
    unsigned s0 = pstart[j], cnt = pcount[j];
    for (unsigned i = t; i < cnt; i += 256) {
      unsigned bits = __float_as_uint(adc_dist(lut_s, sorted_code[s0 + i]));
      if ((int)(bits >> 19) == T) atomicAdd(&hist[(bits >> 7) & 0xFFFu], 1u);
    }
  }
  __syncthreads();
  {
    const unsigned R2 = TOPK - cbelow;
    unsigned mysum = 0;
    for (int i = 0; i < 16; ++i) mysum += hist[t * 16 + i];
    part[t] = mysum;
    __syncthreads();
    for (int off = 1; off < 256; off <<= 1) {
      unsigned v = (t >= off) ? part[t - off] : 0u;
      __syncthreads();
      part[t] += v;
      __syncthreads();
    }
    unsigned incl = part[t], excl = incl - mysum;
    if (excl < R2 && R2 <= incl) {
      unsigned c = excl;
      for (int i = 0; i < 16; ++i) {
        unsigned h = hist[t * 16 + i];
        if (c + h >= R2) { sT2 = t * 16 + i; break; }
        c += h;
      }
    }
  }
  __syncthreads();
  const int T2 = sT2;

  // pass 3: collect survivors (superset of stable top-100 by construction)
  for (int j = 0; j < NPROBE; ++j) {
    unsigned s0 = pstart[j], cnt = pcount[j];
    for (unsigned i = t; i < cnt; i += 256) {
      unsigned bits = __float_as_uint(adc_dist(lut_s, sorted_code[s0 + i]));
      int bin = (int)(bits >> 19);
      int sub = (int)((bits >> 7) & 0xFFFu);
      if (bin < T || (bin == T && sub <= T2)) {
        unsigned p = atomicAdd(&scnt, 1u);
        if (p < COLL_CAP)
          coll[p] = ((unsigned long long)bits << 32) | (unsigned)sorted_n[s0 + i];
      }
    }
  }
  __syncthreads();

  // exact rank by (fp32 bits, index) u64 — stable ascending argsort semantics
  unsigned cnt = scnt;
  if (cnt > COLL_CAP) cnt = COLL_CAP;
  for (unsigned i = t; i < cnt; i += 256) {
    unsigned long long key = coll[i];
    unsigned r = 0;
    for (unsigned j = 0; j < cnt; ++j) r += (coll[j] < key) ? 1u : 0u;
    if (r < TOPK) out[qi * TOPK + r] = (int)(key & 0xffffffffULL);
  }
}

extern "C" void kernel_launch(void* const* d_in, const int* in_sizes, int n_in,
                              void* d_out, int out_size, void* d_ws, size_t ws_size,
                              hipStream_t stream) {
  const float* queries   = (const float*)d_in[0];
  const float* centroids = (const float*)d_in[1];
  const float* codebooks = (const float*)d_in[2];
  const int*   db_codes  = (const int*)d_in[3];
  const int*   db_list   = (const int*)d_in[4];
  const int N = in_sizes[4];
  const int Q = in_sizes[0] / DDIM;
  int* out = (int*)d_out;

  char* p = (char*)d_ws;
  float* lut_g = (float*)p;                 p += (size_t)Q * MSUB * KCODE * 4;
  int* probed_g = (int*)p;                  p += (size_t)Q * NPROBE * 4;
  unsigned* counts = (unsigned*)p;          p += NLIST * 4;
  unsigned* cursor = (unsigned*)p;          p += NLIST * 4;
  unsigned* bstart = (unsigned*)p;          p += (NLIST + 4) * 4; // 1025 used, padded
  int* sorted_n = (int*)p;                  p += (((size_t)N * 4) + 255) / 256 * 256;
  unsigned long long* sorted_code = (unsigned long long*)p; p += (size_t)N * 8;

  hipMemsetAsync(counts, 0, (size_t)NLIST * 4 * 2, stream); // counts + cursor

  k_coarse<<<Q, 256, 0, stream>>>(queries, centroids, probed_g);
  k_lut<<<Q, 256, 0, stream>>>(queries, codebooks, lut_g);
  k_hist<<<256, 256, 0, stream>>>(db_list, N, counts);
  k_scan<<<1, 1024, 0, stream>>>(counts, bstart);
  k_scatter<<<(N + 255) / 256, 256, 0, stream>>>(db_list, db_codes, N, bstart, cursor,
                                                 sorted_n, sorted_code);
  k_search<<<Q, 256, 0, stream>>>(lut_g, probed_g, bstart, sorted_n, sorted_code, out);
}

// Round 14
// 176.893 us; speedup vs baseline: 1.3215x; 1.3215x over previous
//
#include <hip/hip_runtime.h>

#define DDIM 128
#define MSUB 8
#define KCODE 256
#define DSUB 16
#define NLIST 1024
#define NPROBE 32
#define TOPK 100
#define HBINS 4096
#define COLL_CAP 2048
#define CCAP 1024
#define RCAP 12

// ==== FROZEN ARITHMETIC (bit-exact vs reference — do not modify) ====

// XLA/LLVM vectorized reduce, n=128, VF=16, IC=4.
__device__ __forceinline__ float xla_sumsq128(const float* x) {
  float s[16];
  #pragma unroll
  for (int j = 0; j < 16; ++j) {
    float p0 = __fmul_rn(x[j],       x[j]);
    float p1 = __fmul_rn(x[j + 16],  x[j + 16]);
    float p2 = __fmul_rn(x[j + 32],  x[j + 32]);
    float p3 = __fmul_rn(x[j + 48],  x[j + 48]);
    float p4 = __fmul_rn(x[j + 64],  x[j + 64]);
    float p5 = __fmul_rn(x[j + 80],  x[j + 80]);
    float p6 = __fmul_rn(x[j + 96],  x[j + 96]);
    float p7 = __fmul_rn(x[j + 112], x[j + 112]);
    float r0 = __fadd_rn(p0, p4);
    float r1 = __fadd_rn(p1, p5);
    float r2 = __fadd_rn(p2, p6);
    float r3 = __fadd_rn(p3, p7);
    s[j] = __fadd_rn(__fadd_rn(r0, r1), __fadd_rn(r2, r3));
  }
  float a[8], b[4], c[2];
  #pragma unroll
  for (int j = 0; j < 8; ++j) a[j] = __fadd_rn(s[j], s[j + 8]);
  #pragma unroll
  for (int j = 0; j < 4; ++j) b[j] = __fadd_rn(a[j], a[j + 4]);
  #pragma unroll
  for (int j = 0; j < 2; ++j) c[j] = __fadd_rn(b[j], b[j + 2]);
  return __fadd_rn(c[0], c[1]);
}

// same arithmetic, chunked loads (low VGPR): r_l from (x[j+16l], x[j+64+16l])
__device__ __forceinline__ float xla_sumsq128_g(const float* __restrict__ cr) {
  float r0[16], r1[16], t01[16];
  #pragma unroll
  for (int j = 0; j < 16; ++j)
    r0[j] = __fadd_rn(__fmul_rn(cr[j], cr[j]), __fmul_rn(cr[j + 64], cr[j + 64]));
  #pragma unroll
  for (int j = 0; j < 16; ++j)
    r1[j] = __fadd_rn(__fmul_rn(cr[j + 16], cr[j + 16]), __fmul_rn(cr[j + 80], cr[j + 80]));
  #pragma unroll
  for (int j = 0; j < 16; ++j) t01[j] = __fadd_rn(r0[j], r1[j]);
  #pragma unroll
  for (int j = 0; j < 16; ++j)
    r0[j] = __fadd_rn(__fmul_rn(cr[j + 32], cr[j + 32]), __fmul_rn(cr[j + 96], cr[j + 96]));
  #pragma unroll
  for (int j = 0; j < 16; ++j)
    r1[j] = __fadd_rn(__fmul_rn(cr[j + 48], cr[j + 48]), __fmul_rn(cr[j + 112], cr[j + 112]));
  float s[16];
  #pragma unroll
  for (int j = 0; j < 16; ++j) s[j] = __fadd_rn(t01[j], __fadd_rn(r0[j], r1[j]));
  float a[8], b[4], c[2];
  #pragma unroll
  for (int j = 0; j < 8; ++j) a[j] = __fadd_rn(s[j], s[j + 8]);
  #pragma unroll
  for (int j = 0; j < 4; ++j) b[j] = __fadd_rn(a[j], a[j + 4]);
  #pragma unroll
  for (int j = 0; j < 2; ++j) c[j] = __fadd_rn(b[j], b[j + 2]);
  return __fadd_rn(c[0], c[1]);
}

// XLA fused mul+reduce, n=16, VF=16: halving shuffle tree.
__device__ __forceinline__ float xla_sumsq16(const float* x) {
  float p[16];
  #pragma unroll
  for (int j = 0; j < 16; ++j) p[j] = __fmul_rn(x[j], x[j]);
  float s8[8], s4[4], s2[2];
  #pragma unroll
  for (int j = 0; j < 8; ++j) s8[j] = __fadd_rn(p[j], p[j + 8]);
  #pragma unroll
  for (int j = 0; j < 4; ++j) s4[j] = __fadd_rn(s8[j], s8[j + 4]);
  #pragma unroll
  for (int j = 0; j < 2; ++j) s2[j] = __fadd_rn(s4[j], s4[j + 2]);
  return __fadd_rn(s2[0], s2[1]);
}

// Eigen GEMM dot: single FMA chain, k ascending
__device__ __forceinline__ float chain_dot16(const float* a, const float* b) {
  float dot = 0.f;
  #pragma unroll
  for (int d = 0; d < DSUB; ++d) dot = __fmaf_rn(a[d], b[d], dot);
  return dot;
}

// fp32 sequential adds m=0..7
__device__ __forceinline__ float adc_dist(const float* lut, unsigned long long code) {
  float d = lut[(unsigned)(code & 255ULL)];
  d = __fadd_rn(d, lut[256  + (unsigned)((code >> 8)  & 255ULL)]);
  d = __fadd_rn(d, lut[512  + (unsigned)((code >> 16) & 255ULL)]);
  d = __fadd_rn(d, lut[768  + (unsigned)((code >> 24) & 255ULL)]);
  d = __fadd_rn(d, lut[1024 + (unsigned)((code >> 32) & 255ULL)]);
  d = __fadd_rn(d, lut[1280 + (unsigned)((code >> 40) & 255ULL)]);
  d = __fadd_rn(d, lut[1536 + (unsigned)((code >> 48) & 255ULL)]);
  d = __fadd_rn(d, lut[1792 + (unsigned)((code >> 56) & 255ULL)]);
  return d;
}

// ==== helpers ====
// block-wide inclusive scan via wave shuffles; wsum must hold >= nwaves entries.
__device__ __forceinline__ unsigned block_scan_incl(unsigned v, volatile unsigned* wsum,
                                                    int t, int nwaves) {
  int lane = t & 63, wid = t >> 6;
  #pragma unroll
  for (int off = 1; off < 64; off <<= 1) {
    unsigned u = __shfl_up(v, off, 64);
    if (lane >= off) v += u;
  }
  if (lane == 63) wsum[wid] = v;
  __syncthreads();
  if (wid == 0 && lane < nwaves) {
    unsigned wv = wsum[lane];
    #pragma unroll
    for (int off = 1; off < 16; off <<= 1) {
      unsigned u = __shfl_up(wv, off, 64);
      if (lane >= off) wv += u;
    }
    wsum[lane] = wv;
  }
  __syncthreads();
  return v + (wid > 0 ? wsum[wid - 1] : 0u);
}

// ---------------- fused coarse + LUT: one block per query ----------------
__global__ __launch_bounds__(256) void k_coarse_lut(const float* __restrict__ queries,
                                                    const float* __restrict__ centroids,
                                                    const float* __restrict__ codebooks,
                                                    float* __restrict__ lut_g,
                                                    int* __restrict__ probed) {
  const int qi = blockIdx.x;
  const int t = threadIdx.x;
  __shared__ float qs[DDIM];
  __shared__ unsigned hist[HBINS];
  __shared__ unsigned long long coll[512];
  __shared__ unsigned wsum[4];
  __shared__ unsigned scnt;
  __shared__ int sT32;
  if (t < DDIM) qs[t] = queries[qi * DDIM + t];
  for (int i = t; i < HBINS; i += 256) hist[i] = 0;
  if (t == 0) { scnt = 0; sT32 = HBINS - 1; }
  __syncthreads();

  // ---- LUT (frozen arithmetic) ----
  for (int j = 0; j < MSUB; ++j) {
    int idx = j * KCODE + t;
    const float* cb = codebooks + (size_t)idx * DSUB;
    const float* qsub = qs + j * DSUB;
    float cbv[DSUB], qv[DSUB];
    #pragma unroll
    for (int d = 0; d < DSUB; ++d) { cbv[d] = cb[d]; qv[d] = qsub[d]; }
    const float qq16 = xla_sumsq16(qv);
    const float cc16 = xla_sumsq16(cbv);
    const float dot16 = chain_dot16(qv, cbv);
    lut_g[(size_t)qi * (MSUB * KCODE) + idx] =
        __fsub_rn(__fadd_rn(qq16, cc16), __fmul_rn(2.0f, dot16));
  }

  // ---- coarse distances: 4 centroids per thread ----
  const float qq = xla_sumsq128(qs);
  unsigned long long keys[4];
  #pragma unroll
  for (int w = 0; w < 4; ++w) {
    int c = t + 256 * w;
    const float* cr = centroids + (size_t)c * DDIM;
    const float cc = xla_sumsq128_g(cr);
    float dot = 0.f;
    #pragma unroll
    for (int d = 0; d < DDIM; ++d) dot = __fmaf_rn(qs[d], cr[d], dot);
    float dist = __fsub_rn(__fadd_rn(qq, cc), __fmul_rn(2.0f, dot));
    unsigned bits = __float_as_uint(dist);
    keys[w] = ((unsigned long long)bits << 32) | (unsigned)c;
    atomicAdd(&hist[bits >> 19], 1u);
  }
  __syncthreads();

  // ---- find threshold bin for rank NPROBE ----
  unsigned mysum = 0;
  #pragma unroll
  for (int i = 0; i < 16; ++i) mysum += hist[t * 16 + i];
  unsigned incl = block_scan_incl(mysum, wsum, t, 4);
  unsigned excl = incl - mysum;
  if (excl < NPROBE && NPROBE <= incl) {
    unsigned c2 = excl;
    for (int i = 0; i < 16; ++i) {
      unsigned h = hist[t * 16 + i];
      if (c2 + h >= NPROBE) { sT32 = t * 16 + i; break; }
      c2 += h;
    }
  }
  __syncthreads();
  const int T32 = sT32;
  #pragma unroll
  for (int w = 0; w < 4; ++w) {
    if ((int)(keys[w] >> 51) <= T32) {
      unsigned p = atomicAdd(&scnt, 1u);
      if (p < 512) coll[p] = keys[w];
    }
  }
  __syncthreads();
  unsigned cnt = scnt; if (cnt > 512) cnt = 512;
  for (unsigned i = t; i < cnt; i += 256) {
    unsigned long long key = coll[i];
    unsigned r = 0;
    for (unsigned j = 0; j < cnt; ++j) r += (coll[j] < key) ? 1u : 0u;
    if (r < NPROBE) probed[qi * NPROBE + r] = (int)(key & 0xffffffffULL);
  }
}

// ---------------- counting sort of db by list id (unchanged) ----------------
__global__ __launch_bounds__(256) void k_hist(const int* __restrict__ db_list, int N,
                                              unsigned* __restrict__ counts) {
  __shared__ unsigned h[NLIST];
  const int t = threadIdx.x;
  for (int i = t; i < NLIST; i += 256) h[i] = 0;
  __syncthreads();
  for (int n = blockIdx.x * 256 + t; n < N; n += gridDim.x * 256)
    atomicAdd(&h[db_list[n]], 1u);
  __syncthreads();
  for (int i = t; i < NLIST; i += 256)
    if (h[i]) atomicAdd(&counts[i], h[i]);
}

__global__ __launch_bounds__(1024) void k_scan(const unsigned* __restrict__ counts,
                                               unsigned* __restrict__ bstart) {
  __shared__ unsigned s[NLIST];
  const int t = threadIdx.x;
  unsigned mine = counts[t];
  s[t] = mine;
  __syncthreads();
  for (int off = 1; off < NLIST; off <<= 1) {
    unsigned v = (t >= off) ? s[t - off] : 0u;
    __syncthreads();
    s[t] += v;
    __syncthreads();
  }
  bstart[t + 1] = s[t];
  if (t == 0) bstart[0] = 0;
}

__global__ __launch_bounds__(256) void k_scatter(const int* __restrict__ db_list,
                                                 const int* __restrict__ db_codes, int N,
                                                 const unsigned* __restrict__ bstart,
                                                 unsigned* __restrict__ cursor,
                                                 int* __restrict__ sorted_n,
                                                 unsigned long long* __restrict__ sorted_code) {
  for (int n = blockIdx.x * 256 + threadIdx.x; n < N; n += gridDim.x * 256) {
    int l = db_list[n];
    unsigned pos = bstart[l] + atomicAdd(&cursor[l], 1u);
    const int* c = db_codes + (size_t)n * MSUB;
    unsigned long long code = 0;
    for (int m = 0; m < MSUB; ++m)
      code |= ((unsigned long long)(unsigned)(c[m] & 255)) << (8 * m);
    sorted_n[pos] = n;
    sorted_code[pos] = code;
  }
}

// ---------------- main search: 1024 threads, single ADC pass ----------------
__global__ __launch_bounds__(1024, 1) void k_search(const float* __restrict__ lut_g,
                                                    const int* __restrict__ probed,
                                                    const unsigned* __restrict__ bstart,
                                                    const int* __restrict__ sorted_n,
                                                    const unsigned long long* __restrict__ sorted_code,
                                                    int* __restrict__ out) {
  const int qi = blockIdx.x;
  const int t = threadIdx.x;
  __shared__ float lut_s[MSUB * KCODE];            // 8 KB
  __shared__ unsigned hist[HBINS];                 // 16 KB
  __shared__ unsigned long long coll[COLL_CAP];    // 16 KB
  __shared__ unsigned pstart[NPROBE], pcum[NPROBE + 1];
  __shared__ unsigned wsum[16];
  __shared__ unsigned scnt;
  __shared__ int sT, sCb, sT2;

  for (int i = t; i < MSUB * KCODE; i += 1024) lut_s[i] = lut_g[(size_t)qi * (MSUB * KCODE) + i];
  if (t < NPROBE) {
    int l = probed[qi * NPROBE + t];
    unsigned s0 = bstart[l];
    pstart[t] = s0;
    pcum[t + 1] = bstart[l + 1] - s0;  // temp: counts
  }
  for (int i = t; i < HBINS; i += 1024) hist[i] = 0;
  if (t == 0) { scnt = 0; sT = HBINS - 1; sCb = 0; sT2 = HBINS - 1; }
  __syncthreads();
  if (t == 0) {
    unsigned acc = 0;
    pcum[0] = 0;
    for (int j = 1; j <= NPROBE; ++j) { acc += pcum[j]; pcum[j] = acc; }
  }
  __syncthreads();
  const unsigned total = pcum[NPROBE];

  // pass 1: compute all distances ONCE, cache bits in registers, histogram
  unsigned regbits[RCAP];
  {
    int s = 0;
    for (unsigned g = t; g < total; g += 1024, ++s) {
      int lo = 0, hi = NPROBE;
      while (hi - lo > 1) { int mid = (lo + hi) >> 1; if (pcum[mid] <= g) lo = mid; else hi = mid; }
      unsigned addr = pstart[lo] + (g - pcum[lo]);
      unsigned bits = __float_as_uint(adc_dist(lut_s, sorted_code[addr]));
      if (s < RCAP) regbits[s] = bits;
      atomicAdd(&hist[bits >> 19], 1u);
    }
  }
  __syncthreads();

  // select T (rank TOPK) + count strictly below
  {
    unsigned mysum = 0;
    #pragma unroll
    for (int i = 0; i < 4; ++i) mysum += hist[t * 4 + i];
    unsigned incl = block_scan_incl(mysum, wsum, t, 16);
    unsigned excl = incl - mysum;
    if (excl < TOPK && TOPK <= incl) {
      unsigned c = excl;
      #pragma unroll
      for (int i = 0; i < 4; ++i) {
        unsigned h = hist[t * 4 + i];
        if (c + h >= TOPK) { sT = t * 4 + i; sCb = (int)c; break; }
        c += h;
      }
    }
  }
  __syncthreads();
  const int T = sT;
  const unsigned cbelow = (unsigned)sCb;
  for (int i = t; i < HBINS; i += 1024) hist[i] = 0;
  __syncthreads();

  // pass 2: refine within bin T (from registers)
  {
    int s = 0;
    for (unsigned g = t; g < total; g += 1024, ++s) {
      unsigned bits;
      if (s < RCAP) bits = regbits[s];
      else {
        int lo = 0, hi = NPROBE;
        while (hi - lo > 1) { int mid = (lo + hi) >> 1; if (pcum[mid] <= g) lo = mid; else hi = mid; }
        bits = __float_as_uint(adc_dist(lut_s, sorted_code[pstart[lo] + (g - pcum[lo])]));
      }
      if ((int)(bits >> 19) == T) atomicAdd(&hist[(bits >> 7) & 0xFFFu], 1u);
    }
  }
  __syncthreads();
  {
    const unsigned R2 = TOPK - cbelow;
    unsigned mysum = 0;
    #pragma unroll
    for (int i = 0; i < 4; ++i) mysum += hist[t * 4 + i];
    unsigned incl = block_scan_incl(mysum, wsum, t, 16);
    unsigned excl = incl - mysum;
    if (excl < R2 && R2 <= incl) {
      unsigned c = excl;
      #pragma unroll
      for (int i = 0; i < 4; ++i) {
        unsigned h = hist[t * 4 + i];
        if (c + h >= R2) { sT2 = t * 4 + i; break; }
        c += h;
      }
    }
  }
  __syncthreads();
  const int T2 = sT2;

  // pass 3: collect survivors (load sorted_n only for survivors)
  {
    int s = 0;
    for (unsigned g = t; g < total; g += 1024, ++s) {
      unsigned bits;
      int lo = -1;
      if (s < RCAP) bits = regbits[s];
      else {
        int l2 = 0, hi = NPROBE;
        while (hi - l2 > 1) { int mid = (l2 + hi) >> 1; if (pcum[mid] <= g) l2 = mid; else hi = mid; }
        lo = l2;
        bits = __float_as_uint(adc_dist(lut_s, sorted_code[pstart[lo] + (g - pcum[lo])]));
      }
      int bin = (int)(bits >> 19);
      int sub = (int)((bits >> 7) & 0xFFFu);
      if (bin < T || (bin == T && sub <= T2)) {
        if (lo < 0) {
          int l2 = 0, hi = NPROBE;
          while (hi - l2 > 1) { int mid = (l2 + hi) >> 1; if (pcum[mid] <= g) l2 = mid; else hi = mid; }
          lo = l2;
        }
        unsigned n = (unsigned)sorted_n[pstart[lo] + (g - pcum[lo])];
        unsigned p = atomicAdd(&scnt, 1u);
        if (p < COLL_CAP) coll[p] = ((unsigned long long)bits << 32) | n;
      }
    }
  }
  __syncthreads();

  // exact rank by (fp32 bits, index)
  unsigned cnt = scnt;
  if (cnt > COLL_CAP) cnt = COLL_CAP;
  for (unsigned i = t; i < cnt; i += 1024) {
    unsigned long long key = coll[i];
    unsigned r = 0;
    for (unsigned j = 0; j < cnt; ++j) r += (coll[j] < key) ? 1u : 0u;
    if (r < TOPK) out[qi * TOPK + r] = (int)(key & 0xffffffffULL);
  }
}

extern "C" void kernel_launch(void* const* d_in, const int* in_sizes, int n_in,
                              void* d_out, int out_size, void* d_ws, size_t ws_size,
                              hipStream_t stream) {
  const float* queries   = (const float*)d_in[0];
  const float* centroids = (const float*)d_in[1];
  const float* codebooks = (const float*)d_in[2];
  const int*   db_codes  = (const int*)d_in[3];
  const int*   db_list   = (const int*)d_in[4];
  const int N = in_sizes[4];
  const int Q = in_sizes[0] / DDIM;
  int* out = (int*)d_out;

  char* p = (char*)d_ws;
  float* lut_g = (float*)p;                 p += (size_t)Q * MSUB * KCODE * 4;
  int* probed_g = (int*)p;                  p += (size_t)Q * NPROBE * 4;
  unsigned* counts = (unsigned*)p;          p += NLIST * 4;
  unsigned* cursor = (unsigned*)p;          p += NLIST * 4;
  unsigned* bstart = (unsigned*)p;          p += (NLIST + 4) * 4;
  int* sorted_n = (int*)p;                  p += (((size_t)N * 4) + 255) / 256 * 256;
  unsigned long long* sorted_code = (unsigned long long*)p; p += (size_t)N * 8;

  hipMemsetAsync(counts, 0, (size_t)NLIST * 4 * 2, stream); // counts + cursor

  k_coarse_lut<<<Q, 256, 0, stream>>>(queries, centroids, codebooks, lut_g, probed_g);
  k_hist<<<256, 256, 0, stream>>>(db_list, N, counts);
  k_scan<<<1, 1024, 0, stream>>>(counts, bstart);
  k_scatter<<<(N + 255) / 256, 256, 0, stream>>>(db_list, db_codes, N, bstart, cursor,
                                                 sorted_n, sorted_code);
  k_search<<<Q, 1024, 0, stream>>>(lut_g, probed_g, bstart, sorted_n, sorted_code, out);
}

// Round 15
// 140.318 us; speedup vs baseline: 1.6659x; 1.2607x over previous
//
#include <hip/hip_runtime.h>

#define DDIM 128
#define MSUB 8
#define KCODE 256
#define DSUB 16
#define NLIST 1024
#define NPROBE 32
#define TOPK 100
#define HBINS 4096
#define COLL_CAP 2048
#define RCAP 12
#define SCHUNK 4096

// ==== FROZEN ARITHMETIC (bit-exact vs reference — do not modify) ====

__device__ __forceinline__ float xla_sumsq128(const float* x) {
  float s[16];
  #pragma unroll
  for (int j = 0; j < 16; ++j) {
    float p0 = __fmul_rn(x[j],       x[j]);
    float p1 = __fmul_rn(x[j + 16],  x[j + 16]);
    float p2 = __fmul_rn(x[j + 32],  x[j + 32]);
    float p3 = __fmul_rn(x[j + 48],  x[j + 48]);
    float p4 = __fmul_rn(x[j + 64],  x[j + 64]);
    float p5 = __fmul_rn(x[j + 80],  x[j + 80]);
    float p6 = __fmul_rn(x[j + 96],  x[j + 96]);
    float p7 = __fmul_rn(x[j + 112], x[j + 112]);
    float r0 = __fadd_rn(p0, p4);
    float r1 = __fadd_rn(p1, p5);
    float r2 = __fadd_rn(p2, p6);
    float r3 = __fadd_rn(p3, p7);
    s[j] = __fadd_rn(__fadd_rn(r0, r1), __fadd_rn(r2, r3));
  }
  float a[8], b[4], c[2];
  #pragma unroll
  for (int j = 0; j < 8; ++j) a[j] = __fadd_rn(s[j], s[j + 8]);
  #pragma unroll
  for (int j = 0; j < 4; ++j) b[j] = __fadd_rn(a[j], a[j + 4]);
  #pragma unroll
  for (int j = 0; j < 2; ++j) c[j] = __fadd_rn(b[j], b[j + 2]);
  return __fadd_rn(c[0], c[1]);
}

// same arithmetic, reads from (cached) global pointer
__device__ __forceinline__ float xla_sumsq128_g(const float* __restrict__ cr) {
  float r0[16], r1[16], t01[16];
  #pragma unroll
  for (int j = 0; j < 16; ++j)
    r0[j] = __fadd_rn(__fmul_rn(cr[j], cr[j]), __fmul_rn(cr[j + 64], cr[j + 64]));
  #pragma unroll
  for (int j = 0; j < 16; ++j)
    r1[j] = __fadd_rn(__fmul_rn(cr[j + 16], cr[j + 16]), __fmul_rn(cr[j + 80], cr[j + 80]));
  #pragma unroll
  for (int j = 0; j < 16; ++j) t01[j] = __fadd_rn(r0[j], r1[j]);
  #pragma unroll
  for (int j = 0; j < 16; ++j)
    r0[j] = __fadd_rn(__fmul_rn(cr[j + 32], cr[j + 32]), __fmul_rn(cr[j + 96], cr[j + 96]));
  #pragma unroll
  for (int j = 0; j < 16; ++j)
    r1[j] = __fadd_rn(__fmul_rn(cr[j + 48], cr[j + 48]), __fmul_rn(cr[j + 112], cr[j + 112]));
  float s[16];
  #pragma unroll
  for (int j = 0; j < 16; ++j) s[j] = __fadd_rn(t01[j], __fadd_rn(r0[j], r1[j]));
  float a[8], b[4], c[2];
  #pragma unroll
  for (int j = 0; j < 8; ++j) a[j] = __fadd_rn(s[j], s[j + 8]);
  #pragma unroll
  for (int j = 0; j < 4; ++j) b[j] = __fadd_rn(a[j], a[j + 4]);
  #pragma unroll
  for (int j = 0; j < 2; ++j) c[j] = __fadd_rn(b[j], b[j + 2]);
  return __fadd_rn(c[0], c[1]);
}

__device__ __forceinline__ float xla_sumsq16(const float* x) {
  float p[16];
  #pragma unroll
  for (int j = 0; j < 16; ++j) p[j] = __fmul_rn(x[j], x[j]);
  float s8[8], s4[4], s2[2];
  #pragma unroll
  for (int j = 0; j < 8; ++j) s8[j] = __fadd_rn(p[j], p[j + 8]);
  #pragma unroll
  for (int j = 0; j < 4; ++j) s4[j] = __fadd_rn(s8[j], s8[j + 4]);
  #pragma unroll
  for (int j = 0; j < 2; ++j) s2[j] = __fadd_rn(s4[j], s4[j + 2]);
  return __fadd_rn(s2[0], s2[1]);
}

__device__ __forceinline__ float chain_dot16(const float* a, const float* b) {
  float dot = 0.f;
  #pragma unroll
  for (int d = 0; d < DSUB; ++d) dot = __fmaf_rn(a[d], b[d], dot);
  return dot;
}

__device__ __forceinline__ float adc_dist(const float* lut, unsigned long long code) {
  float d = lut[(unsigned)(code & 255ULL)];
  d = __fadd_rn(d, lut[256  + (unsigned)((code >> 8)  & 255ULL)]);
  d = __fadd_rn(d, lut[512  + (unsigned)((code >> 16) & 255ULL)]);
  d = __fadd_rn(d, lut[768  + (unsigned)((code >> 24) & 255ULL)]);
  d = __fadd_rn(d, lut[1024 + (unsigned)((code >> 32) & 255ULL)]);
  d = __fadd_rn(d, lut[1280 + (unsigned)((code >> 40) & 255ULL)]);
  d = __fadd_rn(d, lut[1536 + (unsigned)((code >> 48) & 255ULL)]);
  d = __fadd_rn(d, lut[1792 + (unsigned)((code >> 56) & 255ULL)]);
  return d;
}

// ==== helpers ====
__device__ __forceinline__ unsigned block_scan_incl(unsigned v, volatile unsigned* wsum,
                                                    int t, int nwaves) {
  int lane = t & 63, wid = t >> 6;
  #pragma unroll
  for (int off = 1; off < 64; off <<= 1) {
    unsigned u = __shfl_up(v, off, 64);
    if (lane >= off) v += u;
  }
  if (lane == 63) wsum[wid] = v;
  __syncthreads();
  if (wid == 0 && lane < nwaves) {
    unsigned wv = wsum[lane];
    #pragma unroll
    for (int off = 1; off < 16; off <<= 1) {
      unsigned u = __shfl_up(wv, off, 64);
      if (lane >= off) wv += u;
    }
    wsum[lane] = wv;
  }
  __syncthreads();
  return v + (wid > 0 ? wsum[wid - 1] : 0u);
}

// ---------------- fused coarse + LUT + db_list histogram ----------------
__global__ __launch_bounds__(256) void k_coarse_lut(const float* __restrict__ queries,
                                                    const float* __restrict__ centroids,
                                                    const float* __restrict__ codebooks,
                                                    const int* __restrict__ db_list, int N,
                                                    float* __restrict__ lut_g,
                                                    int* __restrict__ probed,
                                                    unsigned* __restrict__ counts) {
  const int qi = blockIdx.x;
  const int t = threadIdx.x;
  __shared__ float qs[DDIM];
  __shared__ unsigned hist[HBINS];
  __shared__ unsigned long long coll[512];
  __shared__ unsigned wsum[4];
  __shared__ unsigned scnt;
  __shared__ int sT32;
  if (t < DDIM) qs[t] = queries[qi * DDIM + t];
  for (int i = t; i < HBINS; i += 256) hist[i] = 0;
  if (t == 0) { scnt = 0; sT32 = HBINS - 1; }
  __syncthreads();

  // ---- LUT (frozen arithmetic) ----
  for (int j = 0; j < MSUB; ++j) {
    int idx = j * KCODE + t;
    const float* cb = codebooks + (size_t)idx * DSUB;
    const float* qsub = qs + j * DSUB;
    float cbv[DSUB], qv[DSUB];
    #pragma unroll
    for (int d = 0; d < DSUB; ++d) { cbv[d] = cb[d]; qv[d] = qsub[d]; }
    const float qq16 = xla_sumsq16(qv);
    const float cc16 = xla_sumsq16(cbv);
    const float dot16 = chain_dot16(qv, cbv);
    lut_g[(size_t)qi * (MSUB * KCODE) + idx] =
        __fsub_rn(__fadd_rn(qq16, cc16), __fmul_rn(2.0f, dot16));
  }

  // ---- coarse distances: 4 centroids per thread ----
  const float qq = xla_sumsq128(qs);
  unsigned long long keys[4];
  #pragma unroll
  for (int w = 0; w < 4; ++w) {
    int c = t + 256 * w;
    const float* cr = centroids + (size_t)c * DDIM;
    const float cc = xla_sumsq128_g(cr);
    float dot = 0.f;
    #pragma unroll
    for (int d = 0; d < DDIM; ++d) dot = __fmaf_rn(qs[d], cr[d], dot);
    float dist = __fsub_rn(__fadd_rn(qq, cc), __fmul_rn(2.0f, dot));
    unsigned bits = __float_as_uint(dist);
    keys[w] = ((unsigned long long)bits << 32) | (unsigned)c;
    atomicAdd(&hist[bits >> 19], 1u);
  }
  __syncthreads();

  // threshold bin for rank NPROBE
  unsigned mysum = 0;
  #pragma unroll
  for (int i = 0; i < 16; ++i) mysum += hist[t * 16 + i];
  unsigned incl = block_scan_incl(mysum, wsum, t, 4);
  unsigned excl = incl - mysum;
  if (excl < NPROBE && NPROBE <= incl) {
    unsigned c2 = excl;
    for (int i = 0; i < 16; ++i) {
      unsigned h = hist[t * 16 + i];
      if (c2 + h >= NPROBE) { sT32 = t * 16 + i; break; }
      c2 += h;
    }
  }
  __syncthreads();
  const int T32 = sT32;
  #pragma unroll
  for (int w = 0; w < 4; ++w) {
    if ((int)(keys[w] >> 51) <= T32) {
      unsigned p = atomicAdd(&scnt, 1u);
      if (p < 512) coll[p] = keys[w];
    }
  }
  __syncthreads();
  unsigned cnt = scnt; if (cnt > 512) cnt = 512;
  for (unsigned i = t; i < cnt; i += 256) {
    unsigned long long key = coll[i];
    unsigned r = 0;
    for (unsigned j = 0; j < cnt; ++j) r += (coll[j] < key) ? 1u : 0u;
    if (r < NPROBE) probed[qi * NPROBE + r] = (int)(key & 0xffffffffULL);
  }
  __syncthreads();

  // ---- fused db_list histogram (reuse hist[0..NLIST-1]) ----
  for (int i = t; i < NLIST; i += 256) hist[i] = 0;
  __syncthreads();
  for (int n = qi * 256 + t; n < N; n += 256 * 256)
    atomicAdd(&hist[db_list[n]], 1u);
  __syncthreads();
  for (int i = t; i < NLIST; i += 256)
    if (hist[i]) atomicAdd(&counts[i], hist[i]);
}

__global__ __launch_bounds__(1024) void k_scan(const unsigned* __restrict__ counts,
                                               unsigned* __restrict__ bstart) {
  __shared__ unsigned s[NLIST];
  const int t = threadIdx.x;
  unsigned mine = counts[t];
  s[t] = mine;
  __syncthreads();
  for (int off = 1; off < NLIST; off <<= 1) {
    unsigned v = (t >= off) ? s[t - off] : 0u;
    __syncthreads();
    s[t] += v;
    __syncthreads();
  }
  bstart[t + 1] = s[t];
  if (t == 0) bstart[0] = 0;
}

// ---------------- block-aggregated bucket scatter, 16B packed ----------------
__global__ __launch_bounds__(256) void k_scatter(const int* __restrict__ db_list,
                                                 const int* __restrict__ db_codes, int N,
                                                 const unsigned* __restrict__ bstart,
                                                 unsigned* __restrict__ cursor,
                                                 int4* __restrict__ pack) {
  __shared__ unsigned lhist[NLIST], lbase[NLIST];
  const int t = threadIdx.x;
  const int base = blockIdx.x * SCHUNK;
  for (int i = t; i < NLIST; i += 256) lhist[i] = 0;
  __syncthreads();
  #pragma unroll
  for (int k = 0; k < SCHUNK / 256; ++k) {
    int n = base + k * 256 + t;
    if (n < N) atomicAdd(&lhist[db_list[n]], 1u);
  }
  __syncthreads();
  for (int i = t; i < NLIST; i += 256) {
    unsigned cnt = lhist[i];
    if (cnt) lbase[i] = bstart[i] + atomicAdd(&cursor[i], cnt);
    lhist[i] = 0;
  }
  __syncthreads();
  #pragma unroll
  for (int k = 0; k < SCHUNK / 256; ++k) {
    int n = base + k * 256 + t;
    if (n < N) {
      int l = db_list[n];
      unsigned pos = lbase[l] + atomicAdd(&lhist[l], 1u);
      const int4* cp = (const int4*)(db_codes + (size_t)n * MSUB);
      int4 c0 = cp[0], c1 = cp[1];
      unsigned lo = (unsigned)(c0.x & 255) | ((unsigned)(c0.y & 255) << 8) |
                    ((unsigned)(c0.z & 255) << 16) | ((unsigned)(c0.w & 255) << 24);
      unsigned hi = (unsigned)(c1.x & 255) | ((unsigned)(c1.y & 255) << 8) |
                    ((unsigned)(c1.z & 255) << 16) | ((unsigned)(c1.w & 255) << 24);
      pack[pos] = make_int4((int)lo, (int)hi, n, 0);
    }
  }
}

// ---------------- main search: 1024 threads, single ADC pass ----------------
__global__ __launch_bounds__(1024, 1) void k_search(const float* __restrict__ lut_g,
                                                    const int* __restrict__ probed,
                                                    const unsigned* __restrict__ bstart,
                                                    const int4* __restrict__ pack,
                                                    int* __restrict__ out) {
  const int qi = blockIdx.x;
  const int t = threadIdx.x;
  __shared__ float lut_s[MSUB * KCODE];
  __shared__ unsigned hist[HBINS];
  __shared__ unsigned long long coll[COLL_CAP];
  __shared__ unsigned pstart[NPROBE], pcum[NPROBE + 1];
  __shared__ unsigned wsum[16];
  __shared__ unsigned scnt;
  __shared__ int sT, sCb, sT2;

  for (int i = t; i < MSUB * KCODE; i += 1024) lut_s[i] = lut_g[(size_t)qi * (MSUB * KCODE) + i];
  if (t < NPROBE) {
    int l = probed[qi * NPROBE + t];
    unsigned s0 = bstart[l];
    pstart[t] = s0;
    pcum[t + 1] = bstart[l + 1] - s0;
  }
  for (int i = t; i < HBINS; i += 1024) hist[i] = 0;
  if (t == 0) { scnt = 0; sT = HBINS - 1; sCb = 0; sT2 = HBINS - 1; }
  __syncthreads();
  if (t == 0) {
    unsigned acc = 0;
    pcum[0] = 0;
    for (int j = 1; j <= NPROBE; ++j) { acc += pcum[j]; pcum[j] = acc; }
  }
  __syncthreads();
  const unsigned total = pcum[NPROBE];

  // pass 1: distances once, bits cached in registers, coarse histogram
  unsigned regbits[RCAP];
  {
    int s = 0;
    for (unsigned g = t; g < total; g += 1024, ++s) {
      int lo = 0, hi = NPROBE;
      while (hi - lo > 1) { int mid = (lo + hi) >> 1; if (pcum[mid] <= g) lo = mid; else hi = mid; }
      unsigned addr = pstart[lo] + (g - pcum[lo]);
      int4 w = pack[addr];
      unsigned long long code = (unsigned)w.x | ((unsigned long long)(unsigned)w.y << 32);
      unsigned bits = __float_as_uint(adc_dist(lut_s, code));
      if (s < RCAP) regbits[s] = bits;
      atomicAdd(&hist[bits >> 19], 1u);
    }
  }
  __syncthreads();

  {
    unsigned mysum = 0;
    #pragma unroll
    for (int i = 0; i < 4; ++i) mysum += hist[t * 4 + i];
    unsigned incl = block_scan_incl(mysum, wsum, t, 16);
    unsigned excl = incl - mysum;
    if (excl < TOPK && TOPK <= incl) {
      unsigned c = excl;
      #pragma unroll
      for (int i = 0; i < 4; ++i) {
        unsigned h = hist[t * 4 + i];
        if (c + h >= TOPK) { sT = t * 4 + i; sCb = (int)c; break; }
        c += h;
      }
    }
  }
  __syncthreads();
  const int T = sT;
  const unsigned cbelow = (unsigned)sCb;
  for (int i = t; i < HBINS; i += 1024) hist[i] = 0;
  __syncthreads();

  // pass 2: refine within bin T (register-cached)
  {
    int s = 0;
    for (unsigned g = t; g < total; g += 1024, ++s) {
      unsigned bits;
      if (s < RCAP) bits = regbits[s];
      else {
        int lo = 0, hi = NPROBE;
        while (hi - lo > 1) { int mid = (lo + hi) >> 1; if (pcum[mid] <= g) lo = mid; else hi = mid; }
        int4 w = pack[pstart[lo] + (g - pcum[lo])];
        unsigned long long code = (unsigned)w.x | ((unsigned long long)(unsigned)w.y << 32);
        bits = __float_as_uint(adc_dist(lut_s, code));
      }
      if ((int)(bits >> 19) == T) atomicAdd(&hist[(bits >> 7) & 0xFFFu], 1u);
    }
  }
  __syncthreads();
  {
    const unsigned R2 = TOPK - cbelow;
    unsigned mysum = 0;
    #pragma unroll
    for (int i = 0; i < 4; ++i) mysum += hist[t * 4 + i];
    unsigned incl = block_scan_incl(mysum, wsum, t, 16);
    unsigned excl = incl - mysum;
    if (excl < R2 && R2 <= incl) {
      unsigned c = excl;
      #pragma unroll
      for (int i = 0; i < 4; ++i) {
        unsigned h = hist[t * 4 + i];
        if (c + h >= R2) { sT2 = t * 4 + i; break; }
        c += h;
      }
    }
  }
  __syncthreads();
  const int T2 = sT2;

  // pass 3: collect survivors
  {
    int s = 0;
    for (unsigned g = t; g < total; g += 1024, ++s) {
      unsigned bits;
      int lo = -1;
      if (s < RCAP) bits = regbits[s];
      else {
        int l2 = 0, hi = NPROBE;
        while (hi - l2 > 1) { int mid = (l2 + hi) >> 1; if (pcum[mid] <= g) l2 = mid; else hi = mid; }
        lo = l2;
        int4 w = pack[pstart[lo] + (g - pcum[lo])];
        unsigned long long code = (unsigned)w.x | ((unsigned long long)(unsigned)w.y << 32);
        bits = __float_as_uint(adc_dist(lut_s, code));
      }
      int bin = (int)(bits >> 19);
      int sub = (int)((bits >> 7) & 0xFFFu);
      if (bin < T || (bin == T && sub <= T2)) {
        if (lo < 0) {
          int l2 = 0, hi = NPROBE;
          while (hi - l2 > 1) { int mid = (l2 + hi) >> 1; if (pcum[mid] <= g) l2 = mid; else hi = mid; }
          lo = l2;
        }
        unsigned n = (unsigned)pack[pstart[lo] + (g - pcum[lo])].z;
        unsigned p = atomicAdd(&scnt, 1u);
        if (p < COLL_CAP) coll[p] = ((unsigned long long)bits << 32) | n;
      }
    }
  }
  __syncthreads();

  unsigned cnt = scnt;
  if (cnt > COLL_CAP) cnt = COLL_CAP;
  for (unsigned i = t; i < cnt; i += 1024) {
    unsigned long long key = coll[i];
    unsigned r = 0;
    for (unsigned j = 0; j < cnt; ++j) r += (coll[j] < key) ? 1u : 0u;
    if (r < TOPK) out[qi * TOPK + r] = (int)(key & 0xffffffffULL);
  }
}

extern "C" void kernel_launch(void* const* d_in, const int* in_sizes, int n_in,
                              void* d_out, int out_size, void* d_ws, size_t ws_size,
                              hipStream_t stream) {
  const float* queries   = (const float*)d_in[0];
  const float* centroids = (const float*)d_in[1];
  const float* codebooks = (const float*)d_in[2];
  const int*   db_codes  = (const int*)d_in[3];
  const int*   db_list   = (const int*)d_in[4];
  const int N = in_sizes[4];
  const int Q = in_sizes[0] / DDIM;
  int* out = (int*)d_out;

  char* p = (char*)d_ws;
  float* lut_g = (float*)p;        p += (size_t)Q * MSUB * KCODE * 4;
  int* probed_g = (int*)p;         p += (size_t)Q * NPROBE * 4;
  unsigned* counts = (unsigned*)p; p += NLIST * 4;
  unsigned* cursor = (unsigned*)p; p += NLIST * 4;
  unsigned* bstart = (unsigned*)p; p += (NLIST + 4) * 4;  // 4112 B, keeps 16B alignment
  int4* pack = (int4*)p;           p += (size_t)N * 16;

  hipMemsetAsync(counts, 0, (size_t)NLIST * 4 * 2, stream); // counts + cursor

  k_coarse_lut<<<Q, 256, 0, stream>>>(queries, centroids, codebooks, db_list, N,
                                      lut_g, probed_g, counts);
  k_scan<<<1, 1024, 0, stream>>>(counts, bstart);
  k_scatter<<<(N + SCHUNK - 1) / SCHUNK, 256, 0, stream>>>(db_list, db_codes, N,
                                                           bstart, cursor, pack);
  k_search<<<Q, 1024, 0, stream>>>(lut_g, probed_g, bstart, pack, out);
}

// Round 16
// 135.605 us; speedup vs baseline: 1.7239x; 1.0348x over previous
//
#include <hip/hip_runtime.h>

#define DDIM 128
#define MSUB 8
#define KCODE 256
#define DSUB 16
#define NLIST 1024
#define NPROBE 32
#define TOPK 100
#define HBINS 4096
#define COLL_CAP 2048
#define RCAP 12
#define SCHUNK 1024

// ==== FROZEN ARITHMETIC (bit-exact vs reference — do not modify) ====

__device__ __forceinline__ float xla_sumsq128(const float* x) {
  float s[16];
  #pragma unroll
  for (int j = 0; j < 16; ++j) {
    float p0 = __fmul_rn(x[j],       x[j]);
    float p1 = __fmul_rn(x[j + 16],  x[j + 16]);
    float p2 = __fmul_rn(x[j + 32],  x[j + 32]);
    float p3 = __fmul_rn(x[j + 48],  x[j + 48]);
    float p4 = __fmul_rn(x[j + 64],  x[j + 64]);
    float p5 = __fmul_rn(x[j + 80],  x[j + 80]);
    float p6 = __fmul_rn(x[j + 96],  x[j + 96]);
    float p7 = __fmul_rn(x[j + 112], x[j + 112]);
    float r0 = __fadd_rn(p0, p4);
    float r1 = __fadd_rn(p1, p5);
    float r2 = __fadd_rn(p2, p6);
    float r3 = __fadd_rn(p3, p7);
    s[j] = __fadd_rn(__fadd_rn(r0, r1), __fadd_rn(r2, r3));
  }
  float a[8], b[4], c[2];
  #pragma unroll
  for (int j = 0; j < 8; ++j) a[j] = __fadd_rn(s[j], s[j + 8]);
  #pragma unroll
  for (int j = 0; j < 4; ++j) b[j] = __fadd_rn(a[j], a[j + 4]);
  #pragma unroll
  for (int j = 0; j < 2; ++j) c[j] = __fadd_rn(b[j], b[j + 2]);
  return __fadd_rn(c[0], c[1]);
}

__device__ __forceinline__ float xla_sumsq16(const float* x) {
  float p[16];
  #pragma unroll
  for (int j = 0; j < 16; ++j) p[j] = __fmul_rn(x[j], x[j]);
  float s8[8], s4[4], s2[2];
  #pragma unroll
  for (int j = 0; j < 8; ++j) s8[j] = __fadd_rn(p[j], p[j + 8]);
  #pragma unroll
  for (int j = 0; j < 4; ++j) s4[j] = __fadd_rn(s8[j], s8[j + 4]);
  #pragma unroll
  for (int j = 0; j < 2; ++j) s2[j] = __fadd_rn(s4[j], s4[j + 2]);
  return __fadd_rn(s2[0], s2[1]);
}

__device__ __forceinline__ float chain_dot16(const float* a, const float* b) {
  float dot = 0.f;
  #pragma unroll
  for (int d = 0; d < DSUB; ++d) dot = __fmaf_rn(a[d], b[d], dot);
  return dot;
}

__device__ __forceinline__ float adc_dist(const float* lut, unsigned long long code) {
  float d = lut[(unsigned)(code & 255ULL)];
  d = __fadd_rn(d, lut[256  + (unsigned)((code >> 8)  & 255ULL)]);
  d = __fadd_rn(d, lut[512  + (unsigned)((code >> 16) & 255ULL)]);
  d = __fadd_rn(d, lut[768  + (unsigned)((code >> 24) & 255ULL)]);
  d = __fadd_rn(d, lut[1024 + (unsigned)((code >> 32) & 255ULL)]);
  d = __fadd_rn(d, lut[1280 + (unsigned)((code >> 40) & 255ULL)]);
  d = __fadd_rn(d, lut[1536 + (unsigned)((code >> 48) & 255ULL)]);
  d = __fadd_rn(d, lut[1792 + (unsigned)((code >> 56) & 255ULL)]);
  return d;
}

// ==== helpers ====
__device__ __forceinline__ unsigned block_scan_incl(unsigned v, volatile unsigned* wsum,
                                                    int t, int nwaves) {
  int lane = t & 63, wid = t >> 6;
  #pragma unroll
  for (int off = 1; off < 64; off <<= 1) {
    unsigned u = __shfl_up(v, off, 64);
    if (lane >= off) v += u;
  }
  if (lane == 63) wsum[wid] = v;
  __syncthreads();
  if (wid == 0 && lane < nwaves) {
    unsigned wv = wsum[lane];
    #pragma unroll
    for (int off = 1; off < 16; off <<= 1) {
      unsigned u = __shfl_up(wv, off, 64);
      if (lane >= off) wv += u;
    }
    wsum[lane] = wv;
  }
  __syncthreads();
  return v + (wid > 0 ? wsum[wid - 1] : 0u);
}

// ---------------- fused coarse + LUT + db_list histogram ----------------
__global__ __launch_bounds__(256) void k_coarse_lut(const float* __restrict__ queries,
                                                    const float* __restrict__ centroids,
                                                    const float* __restrict__ codebooks,
                                                    const int* __restrict__ db_list, int N,
                                                    float* __restrict__ lut_g,
                                                    int* __restrict__ probed,
                                                    unsigned* __restrict__ counts) {
  const int qi = blockIdx.x;
  const int t = threadIdx.x;
  __shared__ float qs[DDIM];
  __shared__ unsigned hist[HBINS];
  __shared__ unsigned long long coll[512];
  __shared__ unsigned wsum[4];
  __shared__ unsigned scnt;
  __shared__ int sT32;
  if (t < DDIM) qs[t] = queries[qi * DDIM + t];
  for (int i = t; i < HBINS; i += 256) hist[i] = 0;
  if (t == 0) { scnt = 0; sT32 = HBINS - 1; }
  __syncthreads();

  // ---- LUT (frozen arithmetic) ----
  for (int j = 0; j < MSUB; ++j) {
    int idx = j * KCODE + t;
    const float* cb = codebooks + (size_t)idx * DSUB;
    const float* qsub = qs + j * DSUB;
    float cbv[DSUB], qv[DSUB];
    #pragma unroll
    for (int d = 0; d < DSUB; ++d) { cbv[d] = cb[d]; qv[d] = qsub[d]; }
    const float qq16 = xla_sumsq16(qv);
    const float cc16 = xla_sumsq16(cbv);
    const float dot16 = chain_dot16(qv, cbv);
    lut_g[(size_t)qi * (MSUB * KCODE) + idx] =
        __fsub_rn(__fadd_rn(qq16, cc16), __fmul_rn(2.0f, dot16));
  }

  // ---- coarse distances: 4 centroids per thread, float4-staged ----
  const float qq = xla_sumsq128(qs);
  unsigned long long keys[4];
  #pragma unroll
  for (int w = 0; w < 4; ++w) {
    int c = t + 256 * w;
    const float* cr = centroids + (size_t)c * DDIM;
    float cbuf[DDIM];
    #pragma unroll
    for (int d = 0; d < DDIM; d += 4) {
      float4 cv = *(const float4*)(cr + d);
      cbuf[d] = cv.x; cbuf[d + 1] = cv.y; cbuf[d + 2] = cv.z; cbuf[d + 3] = cv.w;
    }
    const float cc = xla_sumsq128(cbuf);
    float dot = 0.f;
    #pragma unroll
    for (int d = 0; d < DDIM; ++d) dot = __fmaf_rn(qs[d], cbuf[d], dot);
    float dist = __fsub_rn(__fadd_rn(qq, cc), __fmul_rn(2.0f, dot));
    unsigned bits = __float_as_uint(dist);
    keys[w] = ((unsigned long long)bits << 32) | (unsigned)c;
    atomicAdd(&hist[bits >> 19], 1u);
  }
  __syncthreads();

  // threshold bin for rank NPROBE
  unsigned mysum = 0;
  #pragma unroll
  for (int i = 0; i < 16; ++i) mysum += hist[t * 16 + i];
  unsigned incl = block_scan_incl(mysum, wsum, t, 4);
  unsigned excl = incl - mysum;
  if (excl < NPROBE && NPROBE <= incl) {
    unsigned c2 = excl;
    for (int i = 0; i < 16; ++i) {
      unsigned h = hist[t * 16 + i];
      if (c2 + h >= NPROBE) { sT32 = t * 16 + i; break; }
      c2 += h;
    }
  }
  __syncthreads();
  const int T32 = sT32;
  #pragma unroll
  for (int w = 0; w < 4; ++w) {
    if ((int)(keys[w] >> 51) <= T32) {
      unsigned p = atomicAdd(&scnt, 1u);
      if (p < 512) coll[p] = keys[w];
    }
  }
  __syncthreads();
  unsigned cnt = scnt; if (cnt > 512) cnt = 512;
  for (unsigned i = t; i < cnt; i += 256) {
    unsigned long long key = coll[i];
    unsigned r = 0;
    for (unsigned j = 0; j < cnt; ++j) r += (coll[j] < key) ? 1u : 0u;
    if (r < NPROBE) probed[qi * NPROBE + r] = (int)(key & 0xffffffffULL);
  }
  __syncthreads();

  // ---- fused db_list histogram (reuse hist[0..NLIST-1]) ----
  for (int i = t; i < NLIST; i += 256) hist[i] = 0;
  __syncthreads();
  for (int n = qi * 256 + t; n < N; n += 256 * 256)
    atomicAdd(&hist[db_list[n]], 1u);
  __syncthreads();
  for (int i = t; i < NLIST; i += 256)
    if (hist[i]) atomicAdd(&counts[i], hist[i]);
}

__global__ __launch_bounds__(1024) void k_scan(const unsigned* __restrict__ counts,
                                               unsigned* __restrict__ bstart) {
  __shared__ unsigned s[NLIST];
  const int t = threadIdx.x;
  unsigned mine = counts[t];
  s[t] = mine;
  __syncthreads();
  for (int off = 1; off < NLIST; off <<= 1) {
    unsigned v = (t >= off) ? s[t - off] : 0u;
    __syncthreads();
    s[t] += v;
    __syncthreads();
  }
  bstart[t + 1] = s[t];
  if (t == 0) bstart[0] = 0;
}

// ---------------- block-aggregated bucket scatter, 16B packed ----------------
__global__ __launch_bounds__(256) void k_scatter(const int* __restrict__ db_list,
                                                 const int* __restrict__ db_codes, int N,
                                                 const unsigned* __restrict__ bstart,
                                                 unsigned* __restrict__ cursor,
                                                 int4* __restrict__ pack) {
  __shared__ unsigned lhist[NLIST], lbase[NLIST];
  const int t = threadIdx.x;
  const int base = blockIdx.x * SCHUNK;
  for (int i = t; i < NLIST; i += 256) lhist[i] = 0;
  __syncthreads();
  #pragma unroll
  for (int k = 0; k < SCHUNK / 256; ++k) {
    int n = base + k * 256 + t;
    if (n < N) atomicAdd(&lhist[db_list[n]], 1u);
  }
  __syncthreads();
  for (int i = t; i < NLIST; i += 256) {
    unsigned cnt = lhist[i];
    if (cnt) lbase[i] = bstart[i] + atomicAdd(&cursor[i], cnt);
    lhist[i] = 0;
  }
  __syncthreads();
  #pragma unroll
  for (int k = 0; k < SCHUNK / 256; ++k) {
    int n = base + k * 256 + t;
    if (n < N) {
      int l = db_list[n];
      unsigned pos = lbase[l] + atomicAdd(&lhist[l], 1u);
      const int4* cp = (const int4*)(db_codes + (size_t)n * MSUB);
      int4 c0 = cp[0], c1 = cp[1];
      unsigned lo = (unsigned)(c0.x & 255) | ((unsigned)(c0.y & 255) << 8) |
                    ((unsigned)(c0.z & 255) << 16) | ((unsigned)(c0.w & 255) << 24);
      unsigned hi = (unsigned)(c1.x & 255) | ((unsigned)(c1.y & 255) << 8) |
                    ((unsigned)(c1.z & 255) << 16) | ((unsigned)(c1.w & 255) << 24);
      pack[pos] = make_int4((int)lo, (int)hi, n, 0);
    }
  }
}

// ---------------- main search: 1024 threads, 2 passes ----------------
__global__ __launch_bounds__(1024, 1) void k_search(const float* __restrict__ lut_g,
                                                    const int* __restrict__ probed,
                                                    const unsigned* __restrict__ bstart,
                                                    const int4* __restrict__ pack,
                                                    int* __restrict__ out) {
  const int qi = blockIdx.x;
  const int t = threadIdx.x;
  __shared__ float lut_s[MSUB * KCODE];
  __shared__ unsigned hist[HBINS];
  __shared__ unsigned long long coll[COLL_CAP];
  __shared__ unsigned pstart[NPROBE], pcum[NPROBE + 1];
  __shared__ unsigned wsum[16];
  __shared__ unsigned scnt;
  __shared__ int sT;

  for (int i = t; i < MSUB * KCODE; i += 1024) lut_s[i] = lut_g[(size_t)qi * (MSUB * KCODE) + i];
  if (t < NPROBE) {
    int l = probed[qi * NPROBE + t];
    unsigned s0 = bstart[l];
    pstart[t] = s0;
    pcum[t + 1] = bstart[l + 1] - s0;
  }
  for (int i = t; i < HBINS; i += 1024) hist[i] = 0;
  if (t == 0) { scnt = 0; sT = HBINS - 1; }
  __syncthreads();
  if (t == 0) {
    unsigned acc = 0;
    pcum[0] = 0;
    for (int j = 1; j <= NPROBE; ++j) { acc += pcum[j]; pcum[j] = acc; }
  }
  __syncthreads();
  const unsigned total = pcum[NPROBE];

  // pass 1: compute distances ONCE, cache bits in registers, coarse histogram
  unsigned regbits[RCAP];
  {
    int s = 0;
    for (unsigned g = t; g < total; g += 1024, ++s) {
      int lo = 0, hi = NPROBE;
      while (hi - lo > 1) { int mid = (lo + hi) >> 1; if (pcum[mid] <= g) lo = mid; else hi = mid; }
      unsigned addr = pstart[lo] + (g - pcum[lo]);
      int4 w = pack[addr];
      unsigned long long code = (unsigned)w.x | ((unsigned long long)(unsigned)w.y << 32);
      unsigned bits = __float_as_uint(adc_dist(lut_s, code));
      if (s < RCAP) regbits[s] = bits;
      atomicAdd(&hist[bits >> 19], 1u);
    }
  }
  __syncthreads();

  // find T = bin containing rank TOPK
  {
    unsigned mysum = 0;
    #pragma unroll
    for (int i = 0; i < 4; ++i) mysum += hist[t * 4 + i];
    unsigned incl = block_scan_incl(mysum, wsum, t, 16);
    unsigned excl = incl - mysum;
    if (excl < TOPK && TOPK <= incl) {
      unsigned c = excl;
      #pragma unroll
      for (int i = 0; i < 4; ++i) {
        unsigned h = hist[t * 4 + i];
        if (c + h >= TOPK) { sT = t * 4 + i; break; }
        c += h;
      }
    }
  }
  __syncthreads();
  const int T = sT;

  // pass 2: collect ALL candidates with bin <= T (superset of top-TOPK)
  {
    int s = 0;
    for (unsigned g = t; g < total; g += 1024, ++s) {
      unsigned bits;
      int lo = -1;
      if (s < RCAP) bits = regbits[s];
      else {
        int l2 = 0, hi = NPROBE;
        while (hi - l2 > 1) { int mid = (l2 + hi) >> 1; if (pcum[mid] <= g) l2 = mid; else hi = mid; }
        lo = l2;
        int4 w = pack[pstart[lo] + (g - pcum[lo])];
        unsigned long long code = (unsigned)w.x | ((unsigned long long)(unsigned)w.y << 32);
        bits = __float_as_uint(adc_dist(lut_s, code));
      }
      if ((int)(bits >> 19) <= T) {
        if (lo < 0) {
          int l2 = 0, hi = NPROBE;
          while (hi - l2 > 1) { int mid = (l2 + hi) >> 1; if (pcum[mid] <= g) l2 = mid; else hi = mid; }
          lo = l2;
        }
        unsigned n = (unsigned)pack[pstart[lo] + (g - pcum[lo])].z;
        unsigned p = atomicAdd(&scnt, 1u);
        if (p < COLL_CAP) coll[p] = ((unsigned long long)bits << 32) | n;
      }
    }
  }
  __syncthreads();

  // exact rank by (fp32 bits, index): global rank == rank within collection
  unsigned cnt = scnt;
  if (cnt > COLL_CAP) cnt = COLL_CAP;
  for (unsigned i = t; i < cnt; i += 1024) {
    unsigned long long key = coll[i];
    unsigned r = 0;
    for (unsigned j = 0; j < cnt; ++j) r += (coll[j] < key) ? 1u : 0u;
    if (r < TOPK) out[qi * TOPK + r] = (int)(key & 0xffffffffULL);
  }
}

extern "C" void kernel_launch(void* const* d_in, const int* in_sizes, int n_in,
                              void* d_out, int out_size, void* d_ws, size_t ws_size,
                              hipStream_t stream) {
  const float* queries   = (const float*)d_in[0];
  const float* centroids = (const float*)d_in[1];
  const float* codebooks = (const float*)d_in[2];
  const int*   db_codes  = (const int*)d_in[3];
  const int*   db_list   = (const int*)d_in[4];
  const int N = in_sizes[4];
  const int Q = in_sizes[0] / DDIM;
  int* out = (int*)d_out;

  char* p = (char*)d_ws;
  float* lut_g = (float*)p;        p += (size_t)Q * MSUB * KCODE * 4;
  int* probed_g = (int*)p;         p += (size_t)Q * NPROBE * 4;
  unsigned* counts = (unsigned*)p; p += NLIST * 4;
  unsigned* cursor = (unsigned*)p; p += NLIST * 4;
  unsigned* bstart = (unsigned*)p; p += (NLIST + 4) * 4;  // keeps 16B alignment
  int4* pack = (int4*)p;           p += (size_t)N * 16;

  hipMemsetAsync(counts, 0, (size_t)NLIST * 4 * 2, stream); // counts + cursor

  k_coarse_lut<<<Q, 256, 0, stream>>>(queries, centroids, codebooks, db_list, N,
                                      lut_g, probed_g, counts);
  k_scan<<<1, 1024, 0, stream>>>(counts, bstart);
  k_scatter<<<(N + SCHUNK - 1) / SCHUNK, 256, 0, stream>>>(db_list, db_codes, N,
                                                           bstart, cursor, pack);
  k_search<<<Q, 1024, 0, stream>>>(lut_g, probed_g, bstart, pack, out);
}